// Round 1
// baseline (661.723 us; speedup 1.0000x reference)
//
#include <hip/hip_runtime.h>
#include <math.h>

#define NX   160
#define N2   25600        // 160*160
#define N3   4096000      // 160^3
#define NB   4
#define TILE 32
#define HALO 4
#define LW   40           // TILE + 2*HALO

// 1D Gaussian taps exp(-d^2/50), d=-4..4 (NOT normalized, matches reference)
__device__ __constant__ float G1[9] = {
    0.72614903f, 0.83527021f, 0.92311635f, 0.98019867f, 1.0f,
    0.98019867f, 0.92311635f, 0.83527021f, 0.72614903f};

// sum of taps that stay in [0,160) at coordinate i (K conv ones, 1D)
__device__ inline float edge_sum(int i) {
    float s = 0.f;
#pragma unroll
    for (int d = 0; d < 9; ++d) {
        int j = i + d - 4;
        s += (j >= 0 && j < NX) ? G1[d] : 0.f;
    }
    return s;
}

// block = 256 threads (4 waves). Reduce NV doubles, one atomicAdd each.
template <int NV>
__device__ inline void block_reduce_atomic(double* vals, double* dst) {
    __shared__ double red[4][NV];
    int lane = threadIdx.x & 63;
    int wave = threadIdx.x >> 6;
#pragma unroll
    for (int v = 0; v < NV; ++v) {
        double x = vals[v];
#pragma unroll
        for (int off = 32; off > 0; off >>= 1) x += __shfl_down(x, off, 64);
        if (lane == 0) red[wave][v] = x;
    }
    __syncthreads();
    if (threadIdx.x == 0) {
#pragma unroll
        for (int v = 0; v < NV; ++v) {
            double s = red[0][v] + red[1][v] + red[2][v] + red[3][v];
            atomicAdd(&dst[v], s);
        }
    }
}

__global__ void init_kernel(double* acc) {
    int i = threadIdx.x;
    if (i < 16) acc[i] = 0.0;
}

// Separable conv of labels along x and y within one z-slice, LDS-tiled.
// Also accumulates per-batch sums: S[3b+0]=sum(p), S[3b+1]=sum(in*p), S[3b+2]=sum(in)
__global__ __launch_bounds__(256) void conv_xy_kernel(
    const float* __restrict__ labels, const float* __restrict__ inputs,
    float* __restrict__ t, double* __restrict__ S) {
    __shared__ float sA[LW][LW];        // raw labels tile + halo
    __shared__ float sB[LW][TILE + 1];  // after x-conv (pad: avoid 33-stride conflicts)

    int bid = blockIdx.x;
    int tileX = bid % 5;
    int tileY = (bid / 5) % 5;
    int zb = bid / 25;            // z + 160*b, 0..639
    int sliceOff = zb * N2;       // == b*N3 + z*N2
    int b = zb / NX;
    int x0 = tileX * TILE, y0 = tileY * TILE;
    int tid = threadIdx.x;

    // load 40x40 with zero-padded halo
    for (int i = tid; i < LW * LW; i += 256) {
        int ly = i / LW, lx = i % LW;
        int gx = x0 + lx - HALO, gy = y0 + ly - HALO;
        float v = 0.f;
        if (gx >= 0 && gx < NX && gy >= 0 && gy < NX)
            v = labels[sliceOff + gy * NX + gx];
        sA[ly][lx] = v;
    }
    __syncthreads();

    // conv along x: 40 rows x 32 cols
    for (int i = tid; i < LW * TILE; i += 256) {
        int ly = i / TILE, ox = i % TILE;
        float s = 0.f;
#pragma unroll
        for (int d = 0; d < 9; ++d) s += G1[d] * sA[ly][ox + d];
        sB[ly][ox] = s;
    }
    __syncthreads();

    // conv along y + global write; fused per-batch mean sums on owned pixels
    double lp = 0.0, lip = 0.0, li = 0.0;
    for (int i = tid; i < TILE * TILE; i += 256) {
        int oy = i / TILE, ox = i % TILE;
        float s = 0.f;
#pragma unroll
        for (int d = 0; d < 9; ++d) s += G1[d] * sB[oy + d][ox];
        int gi = sliceOff + (y0 + oy) * NX + (x0 + ox);
        t[gi] = s;
        float p = sA[oy + HALO][ox + HALO];
        float in = inputs[gi];
        lp += (double)p;
        lip += (double)in * (double)p;
        li += (double)in;
    }
    double vals[3] = {lp, lip, li};
    block_reduce_atomic<3>(vals, S + 3 * b);
}

// z-conv via register sliding window + full fused reduction.
// acc4: {num0, den0, num1, den1}
__global__ __launch_bounds__(256) void conv_z_reduce_kernel(
    const float* __restrict__ t, const float* __restrict__ labels,
    const float* __restrict__ inputs, const double* __restrict__ S,
    double* __restrict__ acc4) {
    int tidg = blockIdx.x * 256 + threadIdx.x;  // 0 .. 409599
    int x = tidg % NX;
    int r = tidg / NX;
    int y = r % NX;
    r /= NX;
    int zc = r % 4;   // z chunk of 40
    int b = r / 4;

    // per-batch means (class 0: p, class 1: 1-p)
    double sp = S[3 * b + 0], sip = S[3 * b + 1], si = S[3 * b + 2];
    const double Nv = (double)N3;
    float m0 = (float)((sip / Nv) / (sp / Nv + 1e-5));
    float m1 = (float)(((si - sip) / Nv) / ((Nv - sp) / Nv + 1e-5));

    float Cxy = edge_sum(x) * edge_sum(y);

    int z0 = zc * 40;
    int base = b * N3 + y * NX + x;

    float win[9];
#pragma unroll
    for (int d = 0; d < 9; ++d) {
        int z = z0 - 4 + d;
        win[d] = (z >= 0 && z < NX) ? t[base + z * N2] : 0.f;
    }

    double n0 = 0, d0 = 0, n1 = 0, d1 = 0;
    for (int z = z0; z < z0 + 40; ++z) {
        float c = 0.f;
#pragma unroll
        for (int d = 0; d < 9; ++d) c += G1[d] * win[d];
        int gi = base + z * N2;
        float p = labels[gi];
        float in = inputs[gi];
        float c1 = Cxy * edge_sum(z) - c;  // conv of (1-p) via conv of ones
        float df0 = in - m0; df0 *= df0;
        float w0 = __expf(-df0 * df0);
        float df1 = in - m1; df1 *= df1;
        float w1 = __expf(-df1 * df1);
        n0 += (double)(c * p * w0);
        d0 += (double)(c * w0);
        n1 += (double)(c1 * (1.f - p) * w1);
        d1 += (double)(c1 * w1);
#pragma unroll
        for (int d = 0; d < 8; ++d) win[d] = win[d + 1];
        int zn = z + 5;
        win[8] = (zn < NX) ? t[base + zn * N2] : 0.f;
    }
    double vals[4] = {n0, d0, n1, d1};
    block_reduce_atomic<4>(vals, acc4);
}

__global__ void finalize_kernel(const double* acc4, float* out) {
    if (threadIdx.x == 0) {
        double r0 = fabs(acc4[0] / (acc4[1] + 1e-6));
        double r1 = fabs(acc4[2] / (acc4[3] + 1e-6));
        out[0] = (float)(2.0 - r0 - r1);
    }
}

extern "C" void kernel_launch(void* const* d_in, const int* in_sizes, int n_in,
                              void* d_out, int out_size, void* d_ws, size_t ws_size,
                              hipStream_t stream) {
    const float* labels = (const float*)d_in[0];
    const float* inputs = (const float*)d_in[1];
    float* out = (float*)d_out;

    double* S = (double*)d_ws;                    // 16 doubles: 12 sums + 4 acc
    float* t = (float*)((char*)d_ws + 256);       // 160^3*4 floats = 65.5 MB

    hipLaunchKernelGGL(init_kernel, dim3(1), dim3(64), 0, stream, S);
    hipLaunchKernelGGL(conv_xy_kernel, dim3(5 * 5 * NX * NB), dim3(256), 0, stream,
                       labels, inputs, t, S);
    hipLaunchKernelGGL(conv_z_reduce_kernel, dim3(409600 / 256), dim3(256), 0, stream,
                       t, labels, inputs, S, S + 12);
    hipLaunchKernelGGL(finalize_kernel, dim3(1), dim3(64), 0, stream, S + 12, out);
}

// Round 2
// 236.921 us; speedup vs baseline: 2.7930x; 2.7930x over previous
//
#include <hip/hip_runtime.h>
#include <math.h>

#define NX   160
#define N2   25600        // 160*160
#define N3   4096000      // 160^3
#define NB   4
#define TILE 32
#define HALO 4
#define LW   40           // TILE + 2*HALO

#define NTILES_XY 16000   // 5*5*160*4
#define TILES_PER_B 4000  // 5*5*160
#define NBLK_Z 800        // (160/4)*160*(160/20)*4 / 256

// 1D Gaussian taps exp(-d^2/50), d=-4..4 (NOT normalized, matches reference)
__device__ __constant__ float G1[9] = {
    0.72614903f, 0.83527021f, 0.92311635f, 0.98019867f, 1.0f,
    0.98019867f, 0.92311635f, 0.83527021f, 0.72614903f};

// sum of taps that stay in [0,160) at coordinate i (K conv ones, 1D)
__device__ inline float edge_sum(int i) {
    float s = 0.f;
#pragma unroll
    for (int d = 0; d < 9; ++d) {
        int j = i + d - 4;
        s += (j >= 0 && j < NX) ? G1[d] : 0.f;
    }
    return s;
}

// block = 256 threads (4 waves). Reduce NV doubles, plain store (NO atomics).
template <int NV>
__device__ inline void block_reduce_store(double* vals, double* dst) {
    __shared__ double red[4][NV];
    int lane = threadIdx.x & 63;
    int wave = threadIdx.x >> 6;
#pragma unroll
    for (int v = 0; v < NV; ++v) {
        double x = vals[v];
#pragma unroll
        for (int off = 32; off > 0; off >>= 1) x += __shfl_down(x, off, 64);
        if (lane == 0) red[wave][v] = x;
    }
    __syncthreads();
    if (threadIdx.x < NV) {
        int v = threadIdx.x;
        dst[v] = red[0][v] + red[1][v] + red[2][v] + red[3][v];
    }
}

// Separable conv of labels along x and y within one z-slice, LDS-tiled.
// Per-block partials (sum p, sum in*p, sum in) -> pS[bid*3 + v]
__global__ __launch_bounds__(256) void conv_xy_kernel(
    const float* __restrict__ labels, const float* __restrict__ inputs,
    float* __restrict__ t, double* __restrict__ pS) {
    __shared__ float sA[LW][LW];        // raw labels tile + halo
    __shared__ float sB[LW][TILE + 1];  // after x-conv

    int bid = blockIdx.x;
    int tileX = bid % 5;
    int tileY = (bid / 5) % 5;
    int zb = bid / 25;            // z + 160*b
    int sliceOff = zb * N2;       // == b*N3 + z*N2
    int x0 = tileX * TILE, y0 = tileY * TILE;
    int tid = threadIdx.x;

    // load 40x40 with zero-padded halo
    for (int i = tid; i < LW * LW; i += 256) {
        int ly = i / LW, lx = i % LW;
        int gx = x0 + lx - HALO, gy = y0 + ly - HALO;
        float v = 0.f;
        if (gx >= 0 && gx < NX && gy >= 0 && gy < NX)
            v = labels[sliceOff + gy * NX + gx];
        sA[ly][lx] = v;
    }
    __syncthreads();

    // conv along x: 40 rows x 32 cols
    for (int i = tid; i < LW * TILE; i += 256) {
        int ly = i / TILE, ox = i % TILE;
        float s = 0.f;
#pragma unroll
        for (int d = 0; d < 9; ++d) s += G1[d] * sA[ly][ox + d];
        sB[ly][ox] = s;
    }
    __syncthreads();

    // conv along y + global write; fused per-batch mean partial sums
    double lp = 0.0, lip = 0.0, li = 0.0;
    for (int i = tid; i < TILE * TILE; i += 256) {
        int oy = i / TILE, ox = i % TILE;
        float s = 0.f;
#pragma unroll
        for (int d = 0; d < 9; ++d) s += G1[d] * sB[oy + d][ox];
        int gi = sliceOff + (y0 + oy) * NX + (x0 + ox);
        t[gi] = s;
        float p = sA[oy + HALO][ox + HALO];
        float in = inputs[gi];
        lp += (double)p;
        lip += (double)in * (double)p;
        li += (double)in;
    }
    double vals[3] = {lp, lip, li};
    block_reduce_store<3>(vals, pS + 3 * bid);
}

// one block per batch: sum 4000 per-tile partials -> S[3b+v]
__global__ __launch_bounds__(256) void reduce_S_kernel(
    const double* __restrict__ pS, double* __restrict__ S) {
    int b = blockIdx.x;
    double v0 = 0, v1 = 0, v2 = 0;
    for (int i = threadIdx.x; i < TILES_PER_B; i += 256) {
        const double* p = pS + 3 * (b * TILES_PER_B + i);
        v0 += p[0]; v1 += p[1]; v2 += p[2];
    }
    double vals[3] = {v0, v1, v2};
    block_reduce_store<3>(vals, S + 3 * b);
}

__device__ inline float4 f4_axpy(float a, float4 b, float4 c) {
    return make_float4(c.x + a * b.x, c.y + a * b.y, c.z + a * b.z, c.w + a * b.w);
}

// z-conv via register sliding window (float4 = 4 x-columns per thread)
// + full fused reduction. Per-block partials {n0,d0,n1,d1} -> pZ[bid*4+v]
__global__ __launch_bounds__(256) void conv_z_reduce_kernel(
    const float* __restrict__ t, const float* __restrict__ labels,
    const float* __restrict__ inputs, const double* __restrict__ S,
    double* __restrict__ pZ) {
    int tidg = blockIdx.x * 256 + threadIdx.x;  // 0 .. 204799
    int x4 = tidg % 40;           // float4 column index; x = 4*x4
    int r = tidg / 40;
    int y = r % NX;
    r /= NX;
    int zc = r % 8;               // z chunk of 20
    int b = r / 8;

    // per-batch means (class 0: p, class 1: 1-p)
    double sp = S[3 * b + 0], sip = S[3 * b + 1], si = S[3 * b + 2];
    const double Nv = (double)N3;
    float m0 = (float)((sip / Nv) / (sp / Nv + 1e-5));
    float m1 = (float)(((si - sip) / Nv) / ((Nv - sp) / Nv + 1e-5));

    int x = x4 * 4;
    float ey = edge_sum(y);
    float4 Cxy = make_float4(edge_sum(x) * ey, edge_sum(x + 1) * ey,
                             edge_sum(x + 2) * ey, edge_sum(x + 3) * ey);

    int z0 = zc * 20;
    int base = b * N3 + y * NX + x;   // float index, 16B-aligned (x%4==0)

    float4 win[9];
#pragma unroll
    for (int d = 0; d < 9; ++d) {
        int z = z0 - 4 + d;
        win[d] = (z >= 0 && z < NX) ? *(const float4*)&t[base + z * N2]
                                    : make_float4(0.f, 0.f, 0.f, 0.f);
    }

    double n0 = 0, d0 = 0, n1 = 0, d1 = 0;
    for (int z = z0; z < z0 + 20; ++z) {
        float4 c = make_float4(0.f, 0.f, 0.f, 0.f);
#pragma unroll
        for (int d = 0; d < 9; ++d) c = f4_axpy(G1[d], win[d], c);
        int gi = base + z * N2;
        float4 p = *(const float4*)&labels[gi];
        float4 in = *(const float4*)&inputs[gi];
        float ez = edge_sum(z);
        float pc[4] = {p.x, p.y, p.z, p.w};
        float ic[4] = {in.x, in.y, in.z, in.w};
        float cc[4] = {c.x, c.y, c.z, c.w};
        float cx[4] = {Cxy.x, Cxy.y, Cxy.z, Cxy.w};
#pragma unroll
        for (int j = 0; j < 4; ++j) {
            float c1 = cx[j] * ez - cc[j];  // conv of (1-p) via conv of ones
            float df0 = ic[j] - m0; df0 *= df0;
            float w0 = __expf(-df0 * df0);
            float df1 = ic[j] - m1; df1 *= df1;
            float w1 = __expf(-df1 * df1);
            n0 += (double)(cc[j] * pc[j] * w0);
            d0 += (double)(cc[j] * w0);
            n1 += (double)(c1 * (1.f - pc[j]) * w1);
            d1 += (double)(c1 * w1);
        }
#pragma unroll
        for (int d = 0; d < 8; ++d) win[d] = win[d + 1];
        int zn = z + 5;
        win[8] = (zn < NX) ? *(const float4*)&t[base + zn * N2]
                           : make_float4(0.f, 0.f, 0.f, 0.f);
    }
    double vals[4] = {n0, d0, n1, d1};
    block_reduce_store<4>(vals, pZ + 4 * blockIdx.x);
}

// single block: sum 800 per-block partials, compute final loss
__global__ __launch_bounds__(256) void finalize_kernel(
    const double* __restrict__ pZ, float* __restrict__ out) {
    double a0 = 0, a1 = 0, a2 = 0, a3 = 0;
    for (int i = threadIdx.x; i < NBLK_Z; i += 256) {
        const double* p = pZ + 4 * i;
        a0 += p[0]; a1 += p[1]; a2 += p[2]; a3 += p[3];
    }
    double vals[4] = {a0, a1, a2, a3};
    __shared__ double acc[4];
    {
        __shared__ double red[4][4];
        int lane = threadIdx.x & 63;
        int wave = threadIdx.x >> 6;
#pragma unroll
        for (int v = 0; v < 4; ++v) {
            double x = vals[v];
#pragma unroll
            for (int off = 32; off > 0; off >>= 1) x += __shfl_down(x, off, 64);
            if (lane == 0) red[wave][v] = x;
        }
        __syncthreads();
        if (threadIdx.x < 4) {
            int v = threadIdx.x;
            acc[v] = red[0][v] + red[1][v] + red[2][v] + red[3][v];
        }
        __syncthreads();
    }
    if (threadIdx.x == 0) {
        double r0 = fabs(acc[0] / (acc[1] + 1e-6));
        double r1 = fabs(acc[2] / (acc[3] + 1e-6));
        out[0] = (float)(2.0 - r0 - r1);
    }
}

extern "C" void kernel_launch(void* const* d_in, const int* in_sizes, int n_in,
                              void* d_out, int out_size, void* d_ws, size_t ws_size,
                              hipStream_t stream) {
    const float* labels = (const float*)d_in[0];
    const float* inputs = (const float*)d_in[1];
    float* out = (float*)d_out;

    // ws layout (all 8B-aligned):
    //   [0)            pS   : 16000*3 doubles = 384000 B
    //   [384000)       S    : 12 doubles      = 96 B
    //   [384096)       pZ   : 800*4 doubles   = 25600 B
    //   [524288)       t    : 4*160^3 floats  = 65,536,000 B
    double* pS = (double*)d_ws;
    double* S  = (double*)((char*)d_ws + 384000);
    double* pZ = (double*)((char*)d_ws + 384096);
    float*  t  = (float*)((char*)d_ws + 524288);

    hipLaunchKernelGGL(conv_xy_kernel, dim3(NTILES_XY), dim3(256), 0, stream,
                       labels, inputs, t, pS);
    hipLaunchKernelGGL(reduce_S_kernel, dim3(NB), dim3(256), 0, stream, pS, S);
    hipLaunchKernelGGL(conv_z_reduce_kernel, dim3(NBLK_Z), dim3(256), 0, stream,
                       t, labels, inputs, S, pZ);
    hipLaunchKernelGGL(finalize_kernel, dim3(1), dim3(256), 0, stream, pZ, out);
}

// Round 3
// 206.384 us; speedup vs baseline: 3.2063x; 1.1480x over previous
//
#include <hip/hip_runtime.h>
#include <math.h>

#define NX   160
#define N2   25600        // 160*160
#define N3   4096000      // 160^3
#define NB   4

#define NTILES_XY 16000   // 5*5*160*4
#define TILES_PER_B 4000  // 5*5*160
#define NBLK_Z 800        // threads: 40 x4 * 160 y * 8 zc * 4 b / 256

#define SA_W 52           // 48 cols + 4 pad floats
#define SB_W 36           // 32 cols + 4 pad floats

// 1D Gaussian taps exp(-d^2/50), d=-4..4 (NOT normalized, matches reference)
__device__ __constant__ float G1[9] = {
    0.72614903f, 0.83527021f, 0.92311635f, 0.98019867f, 1.0f,
    0.98019867f, 0.92311635f, 0.83527021f, 0.72614903f};

// edge sums: FULL - missing taps at low/high boundary
#define ES_FULL 7.92946852f
__device__ __constant__ float ES_M[4] = {3.46473426f, 2.48453559f, 1.56141924f,
                                         0.72614903f};
__device__ inline float edge_sum(int i) {
    float s = ES_FULL;
    if (i < 4) s -= ES_M[i];
    if (i > NX - 5) s -= ES_M[NX - 1 - i];
    return s;
}

__device__ inline float4 f4_zero() { return make_float4(0.f, 0.f, 0.f, 0.f); }
__device__ inline float4 f4_axpy(float a, float4 b, float4 c) {
    return make_float4(c.x + a * b.x, c.y + a * b.y, c.z + a * b.z, c.w + a * b.w);
}

// block = 256 threads (4 waves). Reduce NV doubles, plain store (NO atomics).
template <int NV>
__device__ inline void block_reduce_store(double* vals, double* dst) {
    __shared__ double red[4][NV];
    int lane = threadIdx.x & 63;
    int wave = threadIdx.x >> 6;
#pragma unroll
    for (int v = 0; v < NV; ++v) {
        double x = vals[v];
#pragma unroll
        for (int off = 32; off > 0; off >>= 1) x += __shfl_down(x, off, 64);
        if (lane == 0) red[wave][v] = x;
    }
    __syncthreads();
    if (threadIdx.x < NV) {
        int v = threadIdx.x;
        dst[v] = red[0][v] + red[1][v] + red[2][v] + red[3][v];
    }
}

// Separable conv of labels along x and y within one z-slice, float4 everywhere.
// Tile: 32x32 outputs. sA rows: gy = y0-4+row (40 rows), cols: gx = x0-8+4*c
// (12 float4 = 48 floats; 8-float halo each side for alignment, 4 used).
// Per-block partials (sum p, sum in*p, sum in) -> pS[bid*3 + v]
__global__ __launch_bounds__(256) void conv_xy_kernel(
    const float* __restrict__ labels, const float* __restrict__ inputs,
    float* __restrict__ t, double* __restrict__ pS) {
    __shared__ float sA[40 * SA_W];
    __shared__ float sB[40 * SB_W];

    int bid = blockIdx.x;
    int tileX = bid % 5;
    int tileY = (bid / 5) % 5;
    int zb = bid / 25;            // z + 160*b
    int sliceOff = zb * N2;       // == b*N3 + z*N2
    int x0 = tileX * 32, y0 = tileY * 32;
    int tid = threadIdx.x;

    // load 40 rows x 12 float4, zero-padded outside the volume
    for (int i = tid; i < 480; i += 256) {
        int row = i / 12, c = i % 12;
        int gx = x0 - 8 + 4 * c;
        int gy = y0 - 4 + row;
        float4 v = f4_zero();
        if (gy >= 0 && gy < NX && gx >= 0 && gx <= NX - 4)
            v = *(const float4*)&labels[sliceOff + gy * NX + gx];
        *(float4*)&sA[row * SA_W + 4 * c] = v;
    }
    __syncthreads();

    // x-conv: 40 rows x 8 float4 outputs; out[k] = sum_d G1[d]*row[4x4+4+k+d]
    for (int i = tid; i < 320; i += 256) {
        int r = i >> 3, x4 = i & 7;
        const float* row = &sA[r * SA_W + 4 * x4];
        float4 a = *(const float4*)&row[4];
        float4 b = *(const float4*)&row[8];
        float4 c = *(const float4*)&row[12];
        float w[12] = {a.x, a.y, a.z, a.w, b.x, b.y, b.z, b.w,
                       c.x, c.y, c.z, c.w};
        float4 o = f4_zero();
#pragma unroll
        for (int d = 0; d < 9; ++d) {
            float g = G1[d];
            o.x += g * w[d];
            o.y += g * w[d + 1];
            o.z += g * w[d + 2];
            o.w += g * w[d + 3];
        }
        *(float4*)&sB[r * SB_W + 4 * x4] = o;
    }
    __syncthreads();

    // y-conv: one float4 output per thread (32 rows x 8 f4) + fused sums
    int oy = tid >> 3, x4 = tid & 7;
    float4 acc = f4_zero();
#pragma unroll
    for (int d = 0; d < 9; ++d) {
        float4 v = *(const float4*)&sB[(oy + d) * SB_W + 4 * x4];
        acc = f4_axpy(G1[d], v, acc);
    }
    int gi = sliceOff + (y0 + oy) * NX + (x0 + 4 * x4);
    *(float4*)&t[gi] = acc;

    float4 p = *(const float4*)&sA[(oy + 4) * SA_W + 4 * x4 + 8];
    float4 in = *(const float4*)&inputs[gi];
    float sp = p.x + p.y + p.z + p.w;
    float sip = in.x * p.x + in.y * p.y + in.z * p.z + in.w * p.w;
    float si = in.x + in.y + in.z + in.w;
    double vals[3] = {(double)sp, (double)sip, (double)si};
    block_reduce_store<3>(vals, pS + 3 * bid);
}

// one block per batch: sum 4000 per-tile partials -> S[3b+v]
__global__ __launch_bounds__(256) void reduce_S_kernel(
    const double* __restrict__ pS, double* __restrict__ S) {
    int b = blockIdx.x;
    double v0 = 0, v1 = 0, v2 = 0;
    for (int i = threadIdx.x; i < TILES_PER_B; i += 256) {
        const double* p = pS + 3 * (b * TILES_PER_B + i);
        v0 += p[0]; v1 += p[1]; v2 += p[2];
    }
    double vals[3] = {v0, v1, v2};
    block_reduce_store<3>(vals, S + 3 * b);
}

// z-conv via register sliding window (float4 = 4 x-columns per thread),
// batched loads (4 z-steps per batch, 12 float4 loads in flight),
// f32 accumulators. Per-block partials {n0,d0,n1,d1} -> pZ[bid*4+v]
__global__ __launch_bounds__(256) void conv_z_reduce_kernel(
    const float* __restrict__ t, const float* __restrict__ labels,
    const float* __restrict__ inputs, const double* __restrict__ S,
    double* __restrict__ pZ) {
    int tidg = blockIdx.x * 256 + threadIdx.x;  // 0 .. 204799
    int x4 = tidg % 40;           // float4 column; x = 4*x4
    int r = tidg / 40;
    int y = r % NX;
    r /= NX;
    int zc = r % 8;               // z chunk of 20
    int b = r / 8;

    // per-batch means (class 0: p, class 1: 1-p)
    double sp = S[3 * b + 0], sip = S[3 * b + 1], si = S[3 * b + 2];
    const double Nv = (double)N3;
    float m0 = (float)((sip / Nv) / (sp / Nv + 1e-5));
    float m1 = (float)(((si - sip) / Nv) / ((Nv - sp) / Nv + 1e-5));

    int x = x4 * 4;
    float ey = edge_sum(y);
    float cx[4] = {edge_sum(x) * ey, edge_sum(x + 1) * ey,
                   edge_sum(x + 2) * ey, edge_sum(x + 3) * ey};

    int z0 = zc * 20;
    int base = b * N3 + y * NX + x;   // float index, 16B-aligned

    float4 win[9];
#pragma unroll
    for (int d = 0; d < 9; ++d) {
        int z = z0 - 4 + d;
        win[d] = (z >= 0 && z < NX) ? *(const float4*)&t[base + z * N2]
                                    : f4_zero();
    }

    float n0 = 0.f, d0 = 0.f, n1 = 0.f, d1 = 0.f;
    for (int zb = 0; zb < 5; ++zb) {
        int z = z0 + 4 * zb;
        float4 tn[4], pv[4], iv[4];
#pragma unroll
        for (int j = 0; j < 4; ++j) {
            int zl = z + j + 5;
            tn[j] = (zl < NX) ? *(const float4*)&t[base + zl * N2] : f4_zero();
            int gi = base + (z + j) * N2;
            pv[j] = *(const float4*)&labels[gi];
            iv[j] = *(const float4*)&inputs[gi];
        }
#pragma unroll
        for (int j = 0; j < 4; ++j) {
            float4 c4 = f4_zero();
#pragma unroll
            for (int d = 0; d < 9; ++d) c4 = f4_axpy(G1[d], win[d], c4);
            float ez = edge_sum(z + j);
            float pc[4] = {pv[j].x, pv[j].y, pv[j].z, pv[j].w};
            float ic[4] = {iv[j].x, iv[j].y, iv[j].z, iv[j].w};
            float cc[4] = {c4.x, c4.y, c4.z, c4.w};
#pragma unroll
            for (int l = 0; l < 4; ++l) {
                float c1 = cx[l] * ez - cc[l];  // conv(1-p) via conv(ones)
                float df0 = ic[l] - m0; df0 *= df0;
                float w0 = __expf(-df0 * df0);
                float df1 = ic[l] - m1; df1 *= df1;
                float w1 = __expf(-df1 * df1);
                n0 += cc[l] * pc[l] * w0;
                d0 += cc[l] * w0;
                n1 += c1 * (1.f - pc[l]) * w1;
                d1 += c1 * w1;
            }
#pragma unroll
            for (int d = 0; d < 8; ++d) win[d] = win[d + 1];
            win[8] = tn[j];
        }
    }
    double vals[4] = {(double)n0, (double)d0, (double)n1, (double)d1};
    block_reduce_store<4>(vals, pZ + 4 * blockIdx.x);
}

// single block: sum 800 per-block partials, compute final loss
__global__ __launch_bounds__(256) void finalize_kernel(
    const double* __restrict__ pZ, float* __restrict__ out) {
    double a0 = 0, a1 = 0, a2 = 0, a3 = 0;
    for (int i = threadIdx.x; i < NBLK_Z; i += 256) {
        const double* p = pZ + 4 * i;
        a0 += p[0]; a1 += p[1]; a2 += p[2]; a3 += p[3];
    }
    __shared__ double red[4][4];
    int lane = threadIdx.x & 63;
    int wave = threadIdx.x >> 6;
    double vals[4] = {a0, a1, a2, a3};
#pragma unroll
    for (int v = 0; v < 4; ++v) {
        double x = vals[v];
#pragma unroll
        for (int off = 32; off > 0; off >>= 1) x += __shfl_down(x, off, 64);
        if (lane == 0) red[wave][v] = x;
    }
    __syncthreads();
    if (threadIdx.x == 0) {
        double acc[4];
#pragma unroll
        for (int v = 0; v < 4; ++v)
            acc[v] = red[0][v] + red[1][v] + red[2][v] + red[3][v];
        double r0 = fabs(acc[0] / (acc[1] + 1e-6));
        double r1 = fabs(acc[2] / (acc[3] + 1e-6));
        out[0] = (float)(2.0 - r0 - r1);
    }
}

extern "C" void kernel_launch(void* const* d_in, const int* in_sizes, int n_in,
                              void* d_out, int out_size, void* d_ws, size_t ws_size,
                              hipStream_t stream) {
    const float* labels = (const float*)d_in[0];
    const float* inputs = (const float*)d_in[1];
    float* out = (float*)d_out;

    // ws layout (all 8B-aligned):
    //   [0)            pS   : 16000*3 doubles = 384000 B
    //   [384000)       S    : 12 doubles      = 96 B
    //   [384096)       pZ   : 800*4 doubles   = 25600 B
    //   [524288)       t    : 4*160^3 floats  = 65,536,000 B
    double* pS = (double*)d_ws;
    double* S  = (double*)((char*)d_ws + 384000);
    double* pZ = (double*)((char*)d_ws + 384096);
    float*  t  = (float*)((char*)d_ws + 524288);

    hipLaunchKernelGGL(conv_xy_kernel, dim3(NTILES_XY), dim3(256), 0, stream,
                       labels, inputs, t, pS);
    hipLaunchKernelGGL(reduce_S_kernel, dim3(NB), dim3(256), 0, stream, pS, S);
    hipLaunchKernelGGL(conv_z_reduce_kernel, dim3(NBLK_Z), dim3(256), 0, stream,
                       t, labels, inputs, S, pZ);
    hipLaunchKernelGGL(finalize_kernel, dim3(1), dim3(256), 0, stream, pZ, out);
}